// Round 2
// baseline (244.296 us; speedup 1.0000x reference)
//
#include <hip/hip_runtime.h>

// Involution: B=16, C=256, H=W=56, mid=64, GROUPS=16, GROUP_SIZE=16, K=3 (KK=9)
// All fp32. Output (16,256,56,56).

#define Cn    256
#define MID   64
#define Hn    56
#define Wn    56
#define HW    3136
#define Bn    16
#define NPIX  (Bn * HW)       // 50176
#define CHW   (Cn * HW)
#define NKK   9
#define NG    16
#define GSZ   16
#define BN_EPS 1e-5f

// ---------------------------------------------------------------------------
// prep: w1f[c*64+o] = w1[o*256+c] * scale[o];  bias1[o] = beta[o]-mean[o]*scale[o]
// ---------------------------------------------------------------------------
__global__ __launch_bounds__(256) void prep_kernel(
    const float* __restrict__ w1,
    const float* __restrict__ gamma,
    const float* __restrict__ beta,
    const float* __restrict__ mean,
    const float* __restrict__ var,
    float* __restrict__ w1f,
    float* __restrict__ bias1) {
  int idx = blockIdx.x * 256 + threadIdx.x;
  if (idx < MID * Cn) {
    int c = idx >> 6;
    int o = idx & 63;
    float scale = gamma[o] / sqrtf(var[o] + BN_EPS);
    w1f[idx] = w1[o * Cn + c] * scale;
  } else if (idx < MID * Cn + MID) {
    int o = idx - MID * Cn;
    float scale = gamma[o] / sqrtf(var[o] + BN_EPS);
    bias1[o] = beta[o] - mean[o] * scale;
  }
}

// ---------------------------------------------------------------------------
// conv1: t[o][gp] = relu(bias1[o] + sum_c x[b,c,hw] * w1f[c][o])
// thread = 1 pixel x 16 outputs (blockIdx.y in 0..3). c unrolled by 8 with
// batched loads for MLP.
// ---------------------------------------------------------------------------
__global__ __launch_bounds__(256) void conv1_kernel(
    const float* __restrict__ x,
    const float* __restrict__ w1f,
    const float* __restrict__ bias1,
    float* __restrict__ t) {
  int gp = blockIdx.x * 256 + threadIdx.x;   // 0..50175 (196*256 exact)
  int o0 = blockIdx.y * 16;
  int b  = gp / HW;
  int hw = gp - b * HW;
  const float* xp = x + (size_t)b * CHW + hw;

  float acc[16];
#pragma unroll
  for (int j = 0; j < 16; ++j) acc[j] = bias1[o0 + j];

  for (int c0 = 0; c0 < Cn; c0 += 8) {
    // batch 8 independent x loads first (MLP)
    float xv[8];
#pragma unroll
    for (int i = 0; i < 8; ++i)
      xv[i] = xp[(size_t)(c0 + i) * HW];

#pragma unroll
    for (int i = 0; i < 8; ++i) {
      const float4* wr = (const float4*)(w1f + (c0 + i) * MID + o0);  // uniform -> s_load
#pragma unroll
      for (int q = 0; q < 4; ++q) {
        float4 w4 = wr[q];
        acc[4 * q + 0] = fmaf(xv[i], w4.x, acc[4 * q + 0]);
        acc[4 * q + 1] = fmaf(xv[i], w4.y, acc[4 * q + 1]);
        acc[4 * q + 2] = fmaf(xv[i], w4.z, acc[4 * q + 2]);
        acc[4 * q + 3] = fmaf(xv[i], w4.w, acc[4 * q + 3]);
      }
    }
  }

#pragma unroll
  for (int j = 0; j < 16; ++j)
    t[(size_t)(o0 + j) * NPIX + gp] = fmaxf(acc[j], 0.0f);
}

// ---------------------------------------------------------------------------
// conv2 + involution fused: thread = 1 pixel x 1 group (blockIdx.y = group)
// Branch-free boundary: clamp address, zero the tap weight.
// ---------------------------------------------------------------------------
__global__ __launch_bounds__(256) void conv2_inv_kernel(
    const float* __restrict__ x,
    const float* __restrict__ t,
    const float* __restrict__ w2,
    const float* __restrict__ b2,
    float* __restrict__ out) {
  int gp = blockIdx.x * 256 + threadIdx.x;
  int g  = blockIdx.y;
  int b  = gp / HW;
  int hw = gp - b * HW;
  int h  = hw / Wn;
  int w  = hw - h * Wn;

  // this pixel's 64 conv1 activations (coalesced: lane = pixel)
  float treg[MID];
  const float* tp = t + gp;
#pragma unroll
  for (int o = 0; o < MID; ++o) treg[o] = tp[(size_t)o * NPIX];

  // --- conv2: 9 per-pixel kernel weights for this group ---
  float wk[NKK];
#pragma unroll
  for (int kk = 0; kk < NKK; ++kk) {
    int o2 = g * NKK + kk;
    float s = b2[o2];
    const float4* w2r = (const float4*)(w2 + o2 * MID);  // uniform row of 64
#pragma unroll
    for (int q = 0; q < 16; ++q) {
      float4 w4 = w2r[q];
      s = fmaf(treg[4 * q + 0], w4.x, s);
      s = fmaf(treg[4 * q + 1], w4.y, s);
      s = fmaf(treg[4 * q + 2], w4.z, s);
      s = fmaf(treg[4 * q + 3], w4.w, s);
    }
    wk[kk] = s;
  }

  // --- involution: 16 channels, 9 taps, branch-free edges ---
  const float* xg = x + (size_t)b * CHW + (size_t)(g * GSZ) * HW;

  float oacc[GSZ];
#pragma unroll
  for (int cc = 0; cc < GSZ; ++cc) oacc[cc] = 0.0f;

#pragma unroll
  for (int kk = 0; kk < NKK; ++kk) {
    int di = kk / 3 - 1;
    int dj = kk % 3 - 1;
    int h2 = h + di;
    int w2v = w + dj;
    bool valid = ((unsigned)h2 < (unsigned)Hn) && ((unsigned)w2v < (unsigned)Wn);
    float wv = valid ? wk[kk] : 0.0f;
    int off = valid ? (h2 * Wn + w2v) : hw;   // clamped, always in-bounds
    const float* xr = xg + off;
#pragma unroll
    for (int cc = 0; cc < GSZ; ++cc)
      oacc[cc] = fmaf(wv, xr[(size_t)cc * HW], oacc[cc]);
  }

  float* op = out + (size_t)b * CHW + (size_t)(g * GSZ) * HW + hw;
#pragma unroll
  for (int cc = 0; cc < GSZ; ++cc)
    op[(size_t)cc * HW] = oacc[cc];
}

// ---------------------------------------------------------------------------
extern "C" void kernel_launch(void* const* d_in, const int* in_sizes, int n_in,
                              void* d_out, int out_size, void* d_ws, size_t ws_size,
                              hipStream_t stream) {
  const float* x     = (const float*)d_in[0];
  const float* w1    = (const float*)d_in[1];
  const float* gamma = (const float*)d_in[2];
  const float* beta  = (const float*)d_in[3];
  const float* mean  = (const float*)d_in[4];
  const float* var   = (const float*)d_in[5];
  const float* w2    = (const float*)d_in[6];
  const float* b2    = (const float*)d_in[7];
  float* out = (float*)d_out;

  // workspace: t (64 x 50176 fp32 = 12.85 MB) | w1f (64 KB) | bias1 (256 B)
  char* ws = (char*)d_ws;
  float* t     = (float*)ws;
  float* w1f   = (float*)(ws + (size_t)MID * NPIX * 4);
  float* bias1 = (float*)(ws + (size_t)MID * NPIX * 4 + (size_t)MID * Cn * 4);

  prep_kernel<<<(MID * Cn + MID + 255) / 256, 256, 0, stream>>>(
      w1, gamma, beta, mean, var, w1f, bias1);
  conv1_kernel<<<dim3(NPIX / 256, 4), 256, 0, stream>>>(x, w1f, bias1, t);
  conv2_inv_kernel<<<dim3(NPIX / 256, NG), 256, 0, stream>>>(x, t, w2, b2, out);
}

// Round 3
// 194.248 us; speedup vs baseline: 1.2577x; 1.2577x over previous
//
#include <hip/hip_runtime.h>

// Involution: B=16, C=256, H=W=56, mid=64, GROUPS=16, GROUP_SIZE=16, K=3 (KK=9)
// All fp32. Output (16,256,56,56).

#define Cn    256
#define MID   64
#define Hn    56
#define Wn    56
#define HW    3136
#define Bn    16
#define NPIX  (Bn * HW)       // 50176
#define CHW   (Cn * HW)
#define NKK   9
#define NG    16
#define GSZ   16
#define PXT   64              // pixels per block (64 divides HW=3136: 49 blocks/batch)
#define BN_EPS 1e-5f

// ---------------------------------------------------------------------------
// prep: w1f[c*64+o] = w1[o*256+c] * scale[o];  bias1[o] = beta[o]-mean[o]*scale[o]
// ---------------------------------------------------------------------------
__global__ __launch_bounds__(256) void prep_kernel(
    const float* __restrict__ w1,
    const float* __restrict__ gamma,
    const float* __restrict__ beta,
    const float* __restrict__ mean,
    const float* __restrict__ var,
    float* __restrict__ w1f,
    float* __restrict__ bias1) {
  int idx = blockIdx.x * 256 + threadIdx.x;
  if (idx < MID * Cn) {
    int c = idx >> 6;
    int o = idx & 63;
    float scale = gamma[o] / sqrtf(var[o] + BN_EPS);
    w1f[idx] = w1[o * Cn + c] * scale;
  } else if (idx < MID * Cn + MID) {
    int o = idx - MID * Cn;
    float scale = gamma[o] / sqrtf(var[o] + BN_EPS);
    bias1[o] = beta[o] - mean[o] * scale;
  }
}

// ---------------------------------------------------------------------------
// conv1: t[o][gp] = relu(bias1[o] + sum_c x[b,c,hw] * w1f[c][o])
// Block = 64 px * 64 outputs. 4 waves; wave w computes outputs w*16..w*16+16.
// x staged in double-buffered LDS -> x read exactly once from global.
// Weight rows are wave-uniform (readfirstlane) -> scalar loads.
// ---------------------------------------------------------------------------
__global__ __launch_bounds__(256) void conv1_kernel(
    const float* __restrict__ x,
    const float* __restrict__ w1f,
    const float* __restrict__ bias1,
    float* __restrict__ t) {
  __shared__ float lx[2][16][PXT];     // 2 x 4 KB

  int tid = threadIdx.x;
  int px  = tid & 63;
  int ocv = tid >> 6;                              // 0..3 (wave id)
  int oc  = __builtin_amdgcn_readfirstlane(ocv);   // force wave-uniform

  int px0 = blockIdx.x * PXT;          // 784 blocks, batch-aligned (49/batch)
  int b   = px0 / HW;
  int hw0 = px0 - b * HW;
  const float* xb = x + (size_t)b * CHW + hw0;

  // preload c-tile 0 into buffer 0
  float r[4];
#pragma unroll
  for (int j = 0; j < 4; ++j) {
    int c = j * 4 + ocv;               // (j*256+tid)>>6
    r[j] = xb[(size_t)c * HW + px];
  }
#pragma unroll
  for (int j = 0; j < 4; ++j) lx[0][j * 4 + ocv][px] = r[j];
  __syncthreads();

  float acc[16];
#pragma unroll
  for (int j = 0; j < 16; ++j) acc[j] = 0.0f;

  for (int k = 0; k < 16; ++k) {       // 16 c-tiles of 16
    int cur = k & 1;
    if (k < 15) {
#pragma unroll
      for (int j = 0; j < 4; ++j) {
        int c = (k + 1) * 16 + j * 4 + ocv;
        r[j] = xb[(size_t)c * HW + px];
      }
    }
#pragma unroll
    for (int c = 0; c < 16; ++c) {
      float xv = lx[cur][c][px];
      const float* wr = w1f + ((k * 16 + c) << 6) + (oc << 4);  // uniform
#pragma unroll
      for (int q = 0; q < 4; ++q) {
        float4 w4 = *(const float4*)(wr + q * 4);
        acc[q * 4 + 0] = fmaf(xv, w4.x, acc[q * 4 + 0]);
        acc[q * 4 + 1] = fmaf(xv, w4.y, acc[q * 4 + 1]);
        acc[q * 4 + 2] = fmaf(xv, w4.z, acc[q * 4 + 2]);
        acc[q * 4 + 3] = fmaf(xv, w4.w, acc[q * 4 + 3]);
      }
    }
    if (k < 15) {
#pragma unroll
      for (int j = 0; j < 4; ++j) lx[1 - cur][j * 4 + ocv][px] = r[j];
    }
    __syncthreads();
  }

#pragma unroll
  for (int j = 0; j < 16; ++j) {
    int o = oc * 16 + j;
    float v = acc[j] + bias1[o];
    t[(size_t)o * NPIX + px0 + px] = fmaxf(v, 0.0f);
  }
}

// ---------------------------------------------------------------------------
// conv2 + involution fused. Block = 64 px, ALL 16 groups.
// Phase 1: stage t[64 mid][64 px] in LDS (t read once from global, total).
// Phase 2: compute all 144 per-pixel kernel weights into LDS (conv2 once/px).
// Phase 3: involution; per-tap offsets computed once/thread, reused for
//          4 groups x 16 channels.
// ---------------------------------------------------------------------------
__global__ __launch_bounds__(256) void conv2_inv_kernel(
    const float* __restrict__ x,
    const float* __restrict__ t,
    const float* __restrict__ w2,
    const float* __restrict__ b2,
    float* __restrict__ out) {
  __shared__ float lt[MID][PXT];        // 16 KB
  __shared__ float lw[NG * NKK][PXT];   // 36 KB

  int tid = threadIdx.x;
  int px  = tid & 63;
  int wvv = tid >> 6;                              // 0..3
  int wvu = __builtin_amdgcn_readfirstlane(wvv);

  int px0 = blockIdx.x * PXT;
  int b   = px0 / HW;
  int hw0 = px0 - b * HW;

  // ---- phase 1: stage t tile ----
#pragma unroll
  for (int j = 0; j < 16; ++j) {
    int o = j * 4 + wvv;
    lt[o][px] = t[(size_t)o * NPIX + px0 + px];
  }
  __syncthreads();

  // ---- phase 2: per-pixel kernel weights, 4 groups per thread ----
  for (int gi = 0; gi < 4; ++gi) {
    int g = wvu + gi * 4;               // wave-uniform
    float a[NKK];
#pragma unroll
    for (int kk = 0; kk < NKK; ++kk) a[kk] = b2[g * NKK + kk];
#pragma unroll 4
    for (int o = 0; o < MID; ++o) {
      float tv = lt[o][px];
      const float* w2o = w2 + o;        // row-major [144][64]
#pragma unroll
      for (int kk = 0; kk < NKK; ++kk)
        a[kk] = fmaf(tv, w2o[(g * NKK + kk) * MID], a[kk]);
    }
#pragma unroll
    for (int kk = 0; kk < NKK; ++kk) lw[g * NKK + kk][px] = a[kk];
  }
  __syncthreads();

  // ---- phase 3: involution ----
  int hw = hw0 + px;
  int h  = hw / Wn;
  int w  = hw - h * Wn;

  int off[NKK];
  unsigned vmask = 0;
#pragma unroll
  for (int kk = 0; kk < NKK; ++kk) {
    int di = kk / 3 - 1;
    int dj = kk % 3 - 1;
    int h2 = h + di;
    int w2v = w + dj;
    bool valid = ((unsigned)h2 < (unsigned)Hn) && ((unsigned)w2v < (unsigned)Wn);
    off[kk] = valid ? (h2 * Wn + w2v) : hw;
    vmask |= (valid ? 1u : 0u) << kk;
  }

  const float* xb = x + (size_t)b * CHW;
  float* ob = out + (size_t)b * CHW + hw;

  for (int gi = 0; gi < 4; ++gi) {
    int g = wvu + gi * 4;
    float wk[NKK];
#pragma unroll
    for (int kk = 0; kk < NKK; ++kk)
      wk[kk] = ((vmask >> kk) & 1u) ? lw[g * NKK + kk][px] : 0.0f;

#pragma unroll 4
    for (int cc = 0; cc < GSZ; ++cc) {
      int c = g * GSZ + cc;
      const float* xc = xb + (size_t)c * HW;
      float a = 0.0f;
#pragma unroll
      for (int kk = 0; kk < NKK; ++kk)
        a = fmaf(wk[kk], xc[off[kk]], a);
      ob[(size_t)c * HW] = a;
    }
  }
}

// ---------------------------------------------------------------------------
extern "C" void kernel_launch(void* const* d_in, const int* in_sizes, int n_in,
                              void* d_out, int out_size, void* d_ws, size_t ws_size,
                              hipStream_t stream) {
  const float* x     = (const float*)d_in[0];
  const float* w1    = (const float*)d_in[1];
  const float* gamma = (const float*)d_in[2];
  const float* beta  = (const float*)d_in[3];
  const float* mean  = (const float*)d_in[4];
  const float* var   = (const float*)d_in[5];
  const float* w2    = (const float*)d_in[6];
  const float* b2    = (const float*)d_in[7];
  float* out = (float*)d_out;

  // workspace: t (64 x 50176 fp32 = 12.85 MB) | w1f (64 KB) | bias1 (256 B)
  char* ws = (char*)d_ws;
  float* t     = (float*)ws;
  float* w1f   = (float*)(ws + (size_t)MID * NPIX * 4);
  float* bias1 = (float*)(ws + (size_t)MID * NPIX * 4 + (size_t)MID * Cn * 4);

  prep_kernel<<<(MID * Cn + MID + 255) / 256, 256, 0, stream>>>(
      w1, gamma, beta, mean, var, w1f, bias1);
  conv1_kernel<<<NPIX / PXT, 256, 0, stream>>>(x, w1f, bias1, t);
  conv2_inv_kernel<<<NPIX / PXT, 256, 0, stream>>>(x, t, w2, b2, out);
}